// Round 6
// baseline (1552.897 us; speedup 1.0000x reference)
//
#include <hip/hip_runtime.h>
#include <stdint.h>

#define N_CL 40000
#define NF   20
#define DD   128
#define SS   512
#define NW   625                 // N_CL / 64
#define PARTN (NW * SS)
#define NEGF (-3.0e38f)
#define DISCOUNT 0.995f
#define ECOEF 0.1f

typedef __attribute__((ext_vector_type(4))) float f32x4;

__device__ __forceinline__ float rl(float v, int k) {
    return __int_as_float(__builtin_amdgcn_readlane(__float_as_int(v), k));
}
__device__ __forceinline__ float rcpf(float x) { return __builtin_amdgcn_rcpf(x); }
__device__ __forceinline__ float sigm(float x) { return rcpf(1.f + __expf(-x)); }
__device__ __forceinline__ float tanh_fast(float x) { return 1.f - 2.f * rcpf(1.f + __expf(2.f * x)); }

// ---------------- pack masks: ballot 64 int32 flags -> one u64 word -------------
__global__ __launch_bounds__(256) void k_pack(const int* __restrict__ sel,
                                              const int* __restrict__ good,
                                              unsigned long long* __restrict__ selw,
                                              unsigned long long* __restrict__ goodw) {
    int wave = (blockIdx.x * 256 + threadIdx.x) >> 6;   // 0..2499
    int lane = threadIdx.x & 63;
    for (int i = 0; i < 128; ++i) {
        int chunk = wave * 128 + i;                     // 0..319999
        int s = chunk / NW;
        int b = chunk - s * NW;
        int idx = s * N_CL + b * 64 + lane;
        unsigned long long bs = __ballot(sel[idx]  != 0);
        unsigned long long bg = __ballot(good[idx] != 0);
        if (lane == 0) { selw[s * NW + b] = bs; goodw[s * NW + b] = bg; }
    }
}

// ---------------- hidden = relu(features @ W1 + b1) ----------------------------
__global__ __launch_bounds__(256) void k_hidden(const float* __restrict__ feat,
                                                const float* __restrict__ W1,
                                                const float* __restrict__ b1,
                                                float* __restrict__ hidden) {
    int t = threadIdx.x;
    int j = t & 127;
    int r = blockIdx.x * 2 + (t >> 7);
    const float* fr = feat + r * NF;
    float acc = b1[j];
#pragma unroll
    for (int f = 0; f < NF; ++f) acc += fr[f] * W1[f * DD + j];
    hidden[r * DD + j] = fmaxf(acc, 0.f);
}

// ---------------- emb = hidden @ W2 + b2  (LDS-tiled register GEMM) ------------
#define EMB_FMA(RR) { f32x4 hvv = *(const f32x4*)&hs[rg * 8 + RR][q]; \
    acc##RR += wv0 * hvv.x + wv1 * hvv.y + wv2 * hvv.z + wv3 * hvv.w; }
#define EMB_ST(RR) *(f32x4*)&emb[(rbase + rg * 8 + RR) * DD + c4 * 4] = acc##RR + bv;

__global__ __launch_bounds__(256) void k_emb(const float* __restrict__ hidden,
                                             const float* __restrict__ W2,
                                             const float* __restrict__ b2,
                                             float* __restrict__ emb) {
    __shared__ float hs[64][132];                     // +4 pad, 33.8 KB
    int t = threadIdx.x;
    int rbase = blockIdx.x * 64;
#pragma unroll
    for (int i = t; i < 2048; i += 256) {             // stage 64x128 hidden tile
        int r = i >> 5, k4 = i & 31;
        *(f32x4*)&hs[r][k4 * 4] = *(const f32x4*)&hidden[(rbase + r) * DD + k4 * 4];
    }
    __syncthreads();
    int c4 = t & 31, rg = t >> 5;
    f32x4 acc0{0,0,0,0}, acc1{0,0,0,0}, acc2{0,0,0,0}, acc3{0,0,0,0},
          acc4{0,0,0,0}, acc5{0,0,0,0}, acc6{0,0,0,0}, acc7{0,0,0,0};
    for (int q = 0; q < DD; q += 4) {
        f32x4 wv0 = *(const f32x4*)&W2[(q + 0) * DD + c4 * 4];
        f32x4 wv1 = *(const f32x4*)&W2[(q + 1) * DD + c4 * 4];
        f32x4 wv2 = *(const f32x4*)&W2[(q + 2) * DD + c4 * 4];
        f32x4 wv3 = *(const f32x4*)&W2[(q + 3) * DD + c4 * 4];
        EMB_FMA(0) EMB_FMA(1) EMB_FMA(2) EMB_FMA(3)
        EMB_FMA(4) EMB_FMA(5) EMB_FMA(6) EMB_FMA(7)
    }
    f32x4 bv = *(const f32x4*)&b2[c4 * 4];
    EMB_ST(0) EMB_ST(1) EMB_ST(2) EMB_ST(3)
    EMB_ST(4) EMB_ST(5) EMB_ST(6) EMB_ST(7)
}

// ---- P2[s][pos][g] = bih[j]+bhh[j] + Wih[j].emb[sel_idx[s]],  j=g*128+pos ----
__global__ __launch_bounds__(256) void k_pgemm(const float* __restrict__ emb,
                                               const int* __restrict__ sel_idx,
                                               const float* __restrict__ Wih,
                                               const float* __restrict__ bih,
                                               const float* __restrict__ bhh,
                                               float* __restrict__ P2) {
    __shared__ __align__(16) float x8[8][DD];
    int t = threadIdx.x;
    int sb = blockIdx.x * 8;
    for (int i = t; i < 8 * DD; i += 256) {
        int sl = i >> 7, k = i & 127;
        x8[sl][k] = emb[sel_idx[sb + sl] * DD + k];
    }
    __syncthreads();
    for (int jj = t; jj < 512; jj += 256) {
        float base = bih[jj] + bhh[jj];
        float acc[8];
#pragma unroll
        for (int s8 = 0; s8 < 8; ++s8) acc[s8] = base;
        const float4* wr = (const float4*)(Wih + jj * DD);
        for (int q = 0; q < 32; ++q) {
            float4 w4 = wr[q];
#pragma unroll
            for (int s8 = 0; s8 < 8; ++s8) {
                const float4* xs = (const float4*)&x8[s8][0];
                float4 xv = xs[q];
                acc[s8] += w4.x * xv.x + w4.y * xv.y + w4.z * xv.z + w4.w * xv.w;
            }
        }
        int pos = jj & 127, g = jj >> 7;
        for (int s8 = 0; s8 < 8; ++s8) P2[(sb + s8) * 512 + pos * 4 + g] = acc[s8];
    }
}

// ---------------- sequential LSTM scan: 1 gate/thread, VGPR-PINNED weights -----
// 512 threads = 8 waves. Thread t owns Whh row t: 32 f32x4 = 128 arch VGPRs,
// pinned each iteration via empty asm "+v" so the allocator cannot demote to
// AGPR (round-5 counter evidence: named float4 alone still gave VGPR=84).
#define MV4(W, HV, L) \
    a0 = fmaf(W.x, rl(HV, (L) + 0), a0); \
    a1 = fmaf(W.y, rl(HV, (L) + 1), a1); \
    a2 = fmaf(W.z, rl(HV, (L) + 2), a2); \
    a3 = fmaf(W.w, rl(HV, (L) + 3), a3);

#define PIN8(A,B,C,D,E,F,G,H) \
    __asm__ volatile("" : "+v"(A), "+v"(B), "+v"(C), "+v"(D), \
                          "+v"(E), "+v"(F), "+v"(G), "+v"(H));

__global__ __launch_bounds__(512, 1) void k_lstm(const float* __restrict__ Whh,
                                                 const float* __restrict__ P2,
                                                 const float* __restrict__ init_h,
                                                 const float* __restrict__ init_c,
                                                 float* __restrict__ H) {
    __shared__ __align__(16) float pbuf[2][8 * 512];   // 32 KB: two 8-step P chunks
    __shared__ __align__(16) float gates_sh[512];      // [pos*4 + gtype]
    __shared__ float h_sh[DD];
    int t = threadIdx.x, w = t >> 6, l = t & 63;

    const f32x4* wr = (const f32x4*)(Whh + t * DD);
    f32x4 w0 = wr[0],  w1 = wr[1],  w2 = wr[2],  w3 = wr[3],
          w4 = wr[4],  w5 = wr[5],  w6 = wr[6],  w7 = wr[7],
          w8 = wr[8],  w9 = wr[9],  w10 = wr[10], w11 = wr[11],
          w12 = wr[12], w13 = wr[13], w14 = wr[14], w15 = wr[15],
          w16 = wr[16], w17 = wr[17], w18 = wr[18], w19 = wr[19],
          w20 = wr[20], w21 = wr[21], w22 = wr[22], w23 = wr[23],
          w24 = wr[24], w25 = wr[25], w26 = wr[26], w27 = wr[27],
          w28 = wr[28], w29 = wr[29], w30 = wr[30], w31 = wr[31];

    auto issue = [&](int cidx, int bufi) {             // stage 8-step P chunk
        if (cidx >= SS / 8) return;
        const float* src = P2 + cidx * 4096 + w * 512 + l * 4;
        float* dst = &pbuf[bufi][w * 512];
#pragma unroll
        for (int i = 0; i < 2; ++i) {
            __builtin_amdgcn_global_load_lds(
                (const __attribute__((address_space(1))) void*)(src + i * 256),
                (__attribute__((address_space(3))) void*)(dst + i * 256),
                16, 0, 0);
        }
    };

    float c = 0.f;
    if (t < DD) { h_sh[t] = init_h[t]; c = init_c[t]; H[t] = init_h[t]; }
    issue(0, 0);
    __syncthreads();

    float hbuf[8];
    int pos = t & 127;
    for (int s = 0; s < SS; ++s) {
        PIN8(w0,  w1,  w2,  w3,  w4,  w5,  w6,  w7)
        PIN8(w8,  w9,  w10, w11, w12, w13, w14, w15)
        PIN8(w16, w17, w18, w19, w20, w21, w22, w23)
        PIN8(w24, w25, w26, w27, w28, w29, w30, w31)
        int buf = (s >> 3) & 1;
        if ((s & 7) == 0) issue((s >> 3) + 1, buf ^ 1);
        float vh0 = h_sh[l], vh1 = h_sh[64 + l];
        float a0 = 0.f, a1 = 0.f, a2 = 0.f, a3 = 0.f;
        MV4(w0,  vh0, 0)  MV4(w1,  vh0, 4)  MV4(w2,  vh0, 8)  MV4(w3,  vh0, 12)
        MV4(w4,  vh0, 16) MV4(w5,  vh0, 20) MV4(w6,  vh0, 24) MV4(w7,  vh0, 28)
        MV4(w8,  vh0, 32) MV4(w9,  vh0, 36) MV4(w10, vh0, 40) MV4(w11, vh0, 44)
        MV4(w12, vh0, 48) MV4(w13, vh0, 52) MV4(w14, vh0, 56) MV4(w15, vh0, 60)
        MV4(w16, vh1, 0)  MV4(w17, vh1, 4)  MV4(w18, vh1, 8)  MV4(w19, vh1, 12)
        MV4(w20, vh1, 16) MV4(w21, vh1, 20) MV4(w22, vh1, 24) MV4(w23, vh1, 28)
        MV4(w24, vh1, 32) MV4(w25, vh1, 36) MV4(w26, vh1, 40) MV4(w27, vh1, 44)
        MV4(w28, vh1, 48) MV4(w29, vh1, 52) MV4(w30, vh1, 56) MV4(w31, vh1, 60)
        gates_sh[pos * 4 + (t >> 7)] = (a0 + a1) + (a2 + a3);
        __syncthreads();
        if (t < DD) {
            float4 pv = *(const float4*)&pbuf[buf][(s & 7) * 512 + t * 4];
            float4 gv = *(const float4*)&gates_sh[t * 4];
            float gi = gv.x + pv.x;
            float gf = gv.y + pv.y;
            float gg = gv.z + pv.z;
            float go = gv.w + pv.w;
            float ii = sigm(gi), ff = sigm(gf), tg = tanh_fast(gg), oo = sigm(go);
            c = ff * c + ii * tg;
            float hn = oo * tanh_fast(c);
            h_sh[t] = hn;
            if (s < SS - 1) {
                hbuf[s & 7] = hn;
                if ((s & 7) == 7) {
#pragma unroll
                    for (int k2 = 0; k2 < 8; ++k2) H[(s - 6 + k2) * DD + t] = hbuf[k2];
                }
            }
        }
        __syncthreads();
    }
    if (t < DD) {
#pragma unroll
        for (int k2 = 0; k2 < 7; ++k2) H[(505 + k2) * DD + t] = hbuf[k2];
    }
}

// ------- phase C: thread=step online softmax, VGPR-PINNED h registers ----------
#define LH(Q) f32x4 h##Q = hr4[Q];
#define DOT(Q, ACC) { f32x4 ev = ((const f32x4*)er)[Q]; \
    ACC = fmaf(ev.x, h##Q.x, ACC); ACC = fmaf(ev.y, h##Q.y, ACC); \
    ACC = fmaf(ev.z, h##Q.z, ACC); ACC = fmaf(ev.w, h##Q.w, ACC); }

__global__ __launch_bounds__(512, 1) void k_logits(const float* __restrict__ emb,
                                                   const float* __restrict__ H,
                                                   const unsigned long long* __restrict__ selw,
                                                   const unsigned long long* __restrict__ goodw,
                                                   float* __restrict__ part) {
    int b = blockIdx.x;          // 0..624
    int s = threadIdx.x;         // step index
    const f32x4* hr4 = (const f32x4*)(H + s * DD);
    LH(0)  LH(1)  LH(2)  LH(3)  LH(4)  LH(5)  LH(6)  LH(7)
    LH(8)  LH(9)  LH(10) LH(11) LH(12) LH(13) LH(14) LH(15)
    LH(16) LH(17) LH(18) LH(19) LH(20) LH(21) LH(22) LH(23)
    LH(24) LH(25) LH(26) LH(27) LH(28) LH(29) LH(30) LH(31)
    unsigned long long sw = selw[s * NW + b];
    unsigned long long gw = goodw[s * NW + b];
    float m = NEGF, se = 0.f, sl = 0.f, slg = 0.f;
    int rowbase = b * 64;
    for (int r = 0; r < 64; ++r) {
        PIN8(h0,  h1,  h2,  h3,  h4,  h5,  h6,  h7)
        PIN8(h8,  h9,  h10, h11, h12, h13, h14, h15)
        PIN8(h16, h17, h18, h19, h20, h21, h22, h23)
        PIN8(h24, h25, h26, h27, h28, h29, h30, h31)
        const float* er = emb + (rowbase + r) * DD;    // block-uniform -> s_load
        float a0 = 0.f, a1 = 0.f, a2 = 0.f, a3 = 0.f;
        DOT(0, a0)  DOT(1, a1)  DOT(2, a2)  DOT(3, a3)
        DOT(4, a0)  DOT(5, a1)  DOT(6, a2)  DOT(7, a3)
        DOT(8, a0)  DOT(9, a1)  DOT(10, a2) DOT(11, a3)
        DOT(12, a0) DOT(13, a1) DOT(14, a2) DOT(15, a3)
        DOT(16, a0) DOT(17, a1) DOT(18, a2) DOT(19, a3)
        DOT(20, a0) DOT(21, a1) DOT(22, a2) DOT(23, a3)
        DOT(24, a0) DOT(25, a1) DOT(26, a2) DOT(27, a3)
        DOT(28, a0) DOT(29, a1) DOT(30, a2) DOT(31, a3)
        float acc = (a0 + a1) + (a2 + a3);
        float selb  = (float)((sw >> r) & 1ull);
        float goodb = (float)((gw >> r) & 1ull);
        float lm = (selb > 0.f) ? acc : NEGF;
        float nm = fmaxf(m, lm);
        float a = __expf(m - nm);
        float bx = selb * __expf(lm - nm);
        se = se * a + bx;
        sl = sl * a + bx * acc;
        m = nm;
        slg += goodb * acc;
    }
    int o = b * SS + s;
    part[0 * PARTN + o] = m;
    part[1 * PARTN + o] = se;
    part[2 * PARTN + o] = sl;
    part[3 * PARTN + o] = slg;
    part[4 * PARTN + o] = (float)__popcll(sw);
    part[5 * PARTN + o] = (float)__popcll(gw);
}

// ---------------- per-step merge of 625 block partials -------------------------
__global__ __launch_bounds__(64) void k_reduce(const float* __restrict__ part,
                                               float* __restrict__ Aout,
                                               float* __restrict__ Bout,
                                               float* __restrict__ actout) {
    int s = blockIdx.x;
    int t = threadIdx.x;     // 64 threads, one wave
    float m = NEGF, se = 0.f, sl = 0.f, slg = 0.f, np = 0.f, ng = 0.f;
    for (int b = t; b < NW; b += 64) {
        int o = b * SS + s;
        float m2  = part[0 * PARTN + o];
        float se2 = part[1 * PARTN + o];
        float sl2 = part[2 * PARTN + o];
        slg += part[3 * PARTN + o];
        np  += part[4 * PARTN + o];
        ng  += part[5 * PARTN + o];
        float nm = fmaxf(m, m2);
        float a = __expf(m - nm), a2 = __expf(m2 - nm);
        se = se * a + se2 * a2;
        sl = sl * a + sl2 * a2;
        m = nm;
    }
    for (int off = 32; off > 0; off >>= 1) {
        float m2  = __shfl_xor(m, off);
        float se2 = __shfl_xor(se, off);
        float sl2 = __shfl_xor(sl, off);
        slg += __shfl_xor(slg, off);
        np  += __shfl_xor(np, off);
        ng  += __shfl_xor(ng, off);
        float nm = fmaxf(m, m2);
        float a = __expf(m - nm), a2 = __expf(m2 - nm);
        se = se * a + se2 * a2;
        sl = sl * a + sl2 * a2;
        m = nm;
    }
    if (t == 0) {
        float lse = m + logf(se);
        float nbad = np - ng;
        int active = (ng > 0.5f) && (nbad > 0.5f);
        float ce = (ng * lse - slg) / fmaxf(ng, 1.f);
        float A = (nbad / fmaxf(np, 1.f)) * ce;
        float minus_ent = sl / se - lse;
        float B = ECOEF * (minus_ent / logf(fmaxf(np, 2.0f)));
        Aout[s] = A; Bout[s] = B; actout[s] = active ? 1.f : 0.f;
    }
}

// ---------------- exact sequential discount prefix + final sum -----------------
__global__ __launch_bounds__(64) void k_final(const float* __restrict__ A,
                                              const float* __restrict__ B,
                                              const float* __restrict__ act,
                                              float* __restrict__ out) {
    int lane = threadIdx.x;
    float loss = 0.f;
    int base = 0;
    for (int ch = 0; ch < 8; ++ch) {
        int s = ch * 64 + lane;
        bool a = act[s] > 0.5f;
        unsigned long long bal = __ballot(a);
        unsigned long long ltmask = (lane == 0) ? 0ull : (~0ull >> (64 - lane));
        int pre = __popcll(bal & ltmask);
        if (a) {
            float f = powf(DISCOUNT, (float)(base + pre));
            loss += f * A[s] + B[s];
        }
        base += __popcll(bal);
    }
    for (int off = 32; off > 0; off >>= 1) loss += __shfl_xor(loss, off);
    if (lane == 0) out[0] = loss / fmaxf((float)base, 1.f);
}

extern "C" void kernel_launch(void* const* d_in, const int* in_sizes, int n_in,
                              void* d_out, int out_size, void* d_ws, size_t ws_size,
                              hipStream_t stream) {
    (void)in_sizes; (void)n_in; (void)out_size; (void)ws_size;
    const float* feat    = (const float*)d_in[0];
    const int*   sel     = (const int*)d_in[1];
    const int*   good    = (const int*)d_in[2];
    const int*   sel_idx = (const int*)d_in[3];
    const float* W1      = (const float*)d_in[4];
    const float* b1      = (const float*)d_in[5];
    const float* W2      = (const float*)d_in[6];
    const float* b2      = (const float*)d_in[7];
    const float* init_h  = (const float*)d_in[8];
    const float* init_c  = (const float*)d_in[9];
    const float* Wih     = (const float*)d_in[10];
    const float* Whh     = (const float*)d_in[11];
    const float* bih     = (const float*)d_in[12];
    const float* bhh     = (const float*)d_in[13];
    float* out = (float*)d_out;
    char* ws = (char*)d_ws;

    float* emb    = (float*)(ws + 0);                         // 20,480,000 B
    float* hidden = (float*)(ws + 20480000);                  // 20,480,000 B
    float* P2     = (float*)(ws + 41025536);                  // 1,048,576 B
    float* H      = (float*)(ws + 42074112);                  // 262,144 B
    unsigned long long* selw  = (unsigned long long*)(ws + 42336256);   // 2,560,000 B
    unsigned long long* goodw = (unsigned long long*)(ws + 44896256);   // 2,560,000 B
    float* part   = (float*)(ws + 47456256);                  // 7,680,000 B
    float* Aarr   = (float*)(ws + 55136256);                  // 2048 B
    float* Barr   = (float*)(ws + 55138304);                  // 2048 B
    float* actarr = (float*)(ws + 55140352);                  // 2048 B

    k_pack  <<<NW, 256, 0, stream>>>(sel, good, selw, goodw);
    k_hidden<<<N_CL / 2, 256, 0, stream>>>(feat, W1, b1, hidden);
    k_emb   <<<NW, 256, 0, stream>>>(hidden, W2, b2, emb);
    k_pgemm <<<64, 256, 0, stream>>>(emb, sel_idx, Wih, bih, bhh, P2);
    k_lstm  <<<1, 512, 0, stream>>>(Whh, P2, init_h, init_c, H);
    k_logits<<<NW, 512, 0, stream>>>(emb, H, selw, goodw, part);
    k_reduce<<<SS, 64, 0, stream>>>(part, Aarr, Barr, actarr);
    k_final <<<1, 64, 0, stream>>>(Aarr, Barr, actarr, out);
}

// Round 7
// 1482.902 us; speedup vs baseline: 1.0472x; 1.0472x over previous
//
#include <hip/hip_runtime.h>
#include <stdint.h>

#define N_CL 40000
#define NF   20
#define DD   128
#define SS   512
#define NW   625                 // N_CL / 64
#define PARTN (NW * SS)
#define NEGF (-3.0e38f)
#define DISCOUNT 0.995f
#define ECOEF 0.1f

typedef __attribute__((ext_vector_type(4))) float f32x4;

__device__ __forceinline__ float rl(float v, int k) {
    return __int_as_float(__builtin_amdgcn_readlane(__float_as_int(v), k));
}
__device__ __forceinline__ float rcpf(float x) { return __builtin_amdgcn_rcpf(x); }
__device__ __forceinline__ float sigm(float x) { return rcpf(1.f + __expf(-x)); }
__device__ __forceinline__ float tanh_fast(float x) { return 1.f - 2.f * rcpf(1.f + __expf(2.f * x)); }

// ------- pack masks: ballot -> u64 words, TRANSPOSED layout [b][s] -------------
__global__ __launch_bounds__(256) void k_pack(const int* __restrict__ sel,
                                              const int* __restrict__ good,
                                              unsigned long long* __restrict__ selw,
                                              unsigned long long* __restrict__ goodw) {
    int wave = (blockIdx.x * 256 + threadIdx.x) >> 6;   // 0..4999
    int lane = threadIdx.x & 63;
    for (int i = 0; i < 64; ++i) {
        int chunk = wave * 64 + i;                      // 0..319999
        int s = chunk / NW;
        int b = chunk - s * NW;
        int idx = s * N_CL + b * 64 + lane;
        unsigned long long bs = __ballot(sel[idx]  != 0);
        unsigned long long bg = __ballot(good[idx] != 0);
        if (lane == 0) { selw[b * SS + s] = bs; goodw[b * SS + s] = bg; }
    }
}

// ---------------- hidden = relu(features @ W1 + b1) ----------------------------
__global__ __launch_bounds__(256) void k_hidden(const float* __restrict__ feat,
                                                const float* __restrict__ W1,
                                                const float* __restrict__ b1,
                                                float* __restrict__ hidden) {
    int t = threadIdx.x;
    int j = t & 127;
    int r = blockIdx.x * 2 + (t >> 7);
    const float* fr = feat + r * NF;
    float acc = b1[j];
#pragma unroll
    for (int f = 0; f < NF; ++f) acc += fr[f] * W1[f * DD + j];
    hidden[r * DD + j] = fmaxf(acc, 0.f);
}

// ---------------- emb = hidden @ W2 + b2  (LDS-tiled register GEMM) ------------
#define EMB_FMA(RR) { f32x4 hvv = *(const f32x4*)&hs[rg * 8 + RR][q]; \
    acc##RR += wv0 * hvv.x + wv1 * hvv.y + wv2 * hvv.z + wv3 * hvv.w; }
#define EMB_ST(RR) *(f32x4*)&emb[(rbase + rg * 8 + RR) * DD + c4 * 4] = acc##RR + bv;

__global__ __launch_bounds__(256) void k_emb(const float* __restrict__ hidden,
                                             const float* __restrict__ W2,
                                             const float* __restrict__ b2,
                                             float* __restrict__ emb) {
    __shared__ float hs[64][132];                     // +4 pad, 33.8 KB
    int t = threadIdx.x;
    int rbase = blockIdx.x * 64;
#pragma unroll
    for (int i = t; i < 2048; i += 256) {             // stage 64x128 hidden tile
        int r = i >> 5, k4 = i & 31;
        *(f32x4*)&hs[r][k4 * 4] = *(const f32x4*)&hidden[(rbase + r) * DD + k4 * 4];
    }
    __syncthreads();
    int c4 = t & 31, rg = t >> 5;
    f32x4 acc0{0,0,0,0}, acc1{0,0,0,0}, acc2{0,0,0,0}, acc3{0,0,0,0},
          acc4{0,0,0,0}, acc5{0,0,0,0}, acc6{0,0,0,0}, acc7{0,0,0,0};
    for (int q = 0; q < DD; q += 4) {
        f32x4 wv0 = *(const f32x4*)&W2[(q + 0) * DD + c4 * 4];
        f32x4 wv1 = *(const f32x4*)&W2[(q + 1) * DD + c4 * 4];
        f32x4 wv2 = *(const f32x4*)&W2[(q + 2) * DD + c4 * 4];
        f32x4 wv3 = *(const f32x4*)&W2[(q + 3) * DD + c4 * 4];
        EMB_FMA(0) EMB_FMA(1) EMB_FMA(2) EMB_FMA(3)
        EMB_FMA(4) EMB_FMA(5) EMB_FMA(6) EMB_FMA(7)
    }
    f32x4 bv = *(const f32x4*)&b2[c4 * 4];
    EMB_ST(0) EMB_ST(1) EMB_ST(2) EMB_ST(3)
    EMB_ST(4) EMB_ST(5) EMB_ST(6) EMB_ST(7)
}

// ---- P2[s][pos][g] = bih[j]+bhh[j] + Wih[j].emb[sel_idx[s]],  j=g*128+pos ----
__global__ __launch_bounds__(256) void k_pgemm(const float* __restrict__ emb,
                                               const int* __restrict__ sel_idx,
                                               const float* __restrict__ Wih,
                                               const float* __restrict__ bih,
                                               const float* __restrict__ bhh,
                                               float* __restrict__ P2) {
    __shared__ __align__(16) float x8[8][DD];
    int t = threadIdx.x;
    int sb = blockIdx.x * 8;
    for (int i = t; i < 8 * DD; i += 256) {
        int sl = i >> 7, k = i & 127;
        x8[sl][k] = emb[sel_idx[sb + sl] * DD + k];
    }
    __syncthreads();
    for (int jj = t; jj < 512; jj += 256) {
        float base = bih[jj] + bhh[jj];
        float acc[8];
#pragma unroll
        for (int s8 = 0; s8 < 8; ++s8) acc[s8] = base;
        const float4* wr = (const float4*)(Wih + jj * DD);
        for (int q = 0; q < 32; ++q) {
            float4 w4 = wr[q];
#pragma unroll
            for (int s8 = 0; s8 < 8; ++s8) {
                const float4* xs = (const float4*)&x8[s8][0];
                float4 xv = xs[q];
                acc[s8] += w4.x * xv.x + w4.y * xv.y + w4.z * xv.z + w4.w * xv.w;
            }
        }
        int pos = jj & 127, g = jj >> 7;
        for (int s8 = 0; s8 < 8; ++s8) P2[(sb + s8) * 512 + pos * 4 + g] = acc[s8];
    }
}

// ------- sequential LSTM scan: 1024 thr, 2 rows x 32 ks / thread ---------------
// Thread t: wave w = t>>6, lane l. kq = w&3 (K quarter), rg = w>>2 (row group).
// Rows rA = rg*128+l, rB = rA+64; ks = kq*32..+32. 16 f32x4 weights = 64 VGPRs
// (below the AGPR-demotion threshold seen at ~128 floats in rounds 1-6).
// One readlane feeds TWO fmas -> matvec issue ~880 cyc/SIMD/step.
#define MVQ(WA, WB, KB) { \
    float s0 = rl(vh, (KB) + 0), s1 = rl(vh, (KB) + 1), \
          s2 = rl(vh, (KB) + 2), s3 = rl(vh, (KB) + 3); \
    aA0 = fmaf(WA.x, s0, aA0); aB0 = fmaf(WB.x, s0, aB0); \
    aA1 = fmaf(WA.y, s1, aA1); aB1 = fmaf(WB.y, s1, aB1); \
    aA0 = fmaf(WA.z, s2, aA0); aB0 = fmaf(WB.z, s2, aB0); \
    aA1 = fmaf(WA.w, s3, aA1); aB1 = fmaf(WB.w, s3, aB1); }

__global__ __launch_bounds__(1024, 1) void k_lstm(const float* __restrict__ Whh,
                                                  const float* __restrict__ P2,
                                                  const float* __restrict__ init_h,
                                                  const float* __restrict__ init_c,
                                                  float* __restrict__ H) {
    __shared__ __align__(16) float pbuf[2][4096];   // 32 KB: two 8-step P chunks
    __shared__ float psum[4][512];                  // [kq][gate j]
    __shared__ float h_sh[DD];
    int t = threadIdx.x, w = t >> 6, l = t & 63;
    int kq = w & 3, rg = w >> 2;
    int rA = rg * 128 + l, rB = rA + 64;

    const f32x4* wra = (const f32x4*)(Whh + rA * DD + kq * 32);
    const f32x4* wrb = (const f32x4*)(Whh + rB * DD + kq * 32);
    f32x4 wa0 = wra[0], wa1 = wra[1], wa2 = wra[2], wa3 = wra[3],
          wa4 = wra[4], wa5 = wra[5], wa6 = wra[6], wa7 = wra[7];
    f32x4 wb0 = wrb[0], wb1 = wrb[1], wb2 = wrb[2], wb3 = wrb[3],
          wb4 = wrb[4], wb5 = wrb[5], wb6 = wrb[6], wb7 = wrb[7];

    auto issue = [&](int cidx, int bufi) {          // stage one 8-step P chunk
        if (cidx >= SS / 8) return;
        const float* src = P2 + cidx * 4096 + w * 256 + l * 4;
        float* dst = &pbuf[bufi][w * 256];
        __builtin_amdgcn_global_load_lds(
            (const __attribute__((address_space(1))) void*)src,
            (__attribute__((address_space(3))) void*)dst, 16, 0, 0);
    };

    float c = 0.f;
    if (t < DD) { h_sh[t] = init_h[t]; c = init_c[t]; H[t] = init_h[t]; }
    issue(0, 0);
    __syncthreads();

    float hbuf[8];
    int hl = kq * 32 + (l & 31);
    for (int s = 0; s < SS; ++s) {
        int buf = (s >> 3) & 1;
        if ((s & 7) == 0) issue((s >> 3) + 1, buf ^ 1);
        float vh = h_sh[hl];                        // lane j holds h[kq*32+j]
        float aA0 = 0.f, aA1 = 0.f, aB0 = 0.f, aB1 = 0.f;
        MVQ(wa0, wb0, 0)  MVQ(wa1, wb1, 4)  MVQ(wa2, wb2, 8)  MVQ(wa3, wb3, 12)
        MVQ(wa4, wb4, 16) MVQ(wa5, wb5, 20) MVQ(wa6, wb6, 24) MVQ(wa7, wb7, 28)
        psum[kq][rA] = aA0 + aA1;                   // stride-1 across lanes
        psum[kq][rB] = aB0 + aB1;
        __syncthreads();
        if (t < DD) {
            float4 pv = *(const float4*)&pbuf[buf][(s & 7) * 512 + t * 4];
            float gi = ((psum[0][t] + psum[1][t]) + (psum[2][t] + psum[3][t])) + pv.x;
            float gf = ((psum[0][128 + t] + psum[1][128 + t]) + (psum[2][128 + t] + psum[3][128 + t])) + pv.y;
            float gg = ((psum[0][256 + t] + psum[1][256 + t]) + (psum[2][256 + t] + psum[3][256 + t])) + pv.z;
            float go = ((psum[0][384 + t] + psum[1][384 + t]) + (psum[2][384 + t] + psum[3][384 + t])) + pv.w;
            float ii = sigm(gi), ff = sigm(gf), tg = tanh_fast(gg), oo = sigm(go);
            c = ff * c + ii * tg;
            float hn = oo * tanh_fast(c);
            h_sh[t] = hn;
            if (s < SS - 1) {
                hbuf[s & 7] = hn;
                if ((s & 7) == 7) {                 // batched H store
#pragma unroll
                    for (int k2 = 0; k2 < 8; ++k2) H[(s - 6 + k2) * DD + t] = hbuf[k2];
                }
            }
        }
        __syncthreads();
    }
    if (t < DD) {                                   // steps 504..510 -> H[505..511]
#pragma unroll
        for (int k2 = 0; k2 < 7; ++k2) H[(505 + k2) * DD + t] = hbuf[k2];
    }
}

// ------- phase C: pair-split online softmax, 16 NAMED f32x4 h-regs/thread ------
// grid 2*NW: b = blk>>1, step-half = blk&1. Threads (2p, 2p+1) share step s;
// e = t&1 owns h[e*64..e*64+64). shfl_xor(1) combines the two half-dots.
#define LHh(Q) f32x4 h##Q = hr4[Q];
#define DOTp(Q, ACC) { f32x4 ev = er4[Q]; \
    ACC = fmaf(ev.x, h##Q.x, ACC); ACC = fmaf(ev.y, h##Q.y, ACC); \
    ACC = fmaf(ev.z, h##Q.z, ACC); ACC = fmaf(ev.w, h##Q.w, ACC); }

__global__ __launch_bounds__(512, 1) void k_logits(const float* __restrict__ emb,
                                                   const float* __restrict__ H,
                                                   const unsigned long long* __restrict__ selw,
                                                   const unsigned long long* __restrict__ goodw,
                                                   float* __restrict__ part) {
    int b = blockIdx.x >> 1;
    int sh = blockIdx.x & 1;
    int t = threadIdx.x, p = t >> 1, e = t & 1;
    int s = sh * 256 + p;
    const f32x4* hr4 = (const f32x4*)(H + s * DD + e * 64);
    LHh(0)  LHh(1)  LHh(2)  LHh(3)  LHh(4)  LHh(5)  LHh(6)  LHh(7)
    LHh(8)  LHh(9)  LHh(10) LHh(11) LHh(12) LHh(13) LHh(14) LHh(15)
    unsigned long long sw = selw[b * SS + s];       // coalesced ([b][s] layout)
    unsigned long long gw = goodw[b * SS + s];
    float m = NEGF, se = 0.f, sl = 0.f, slg = 0.f;
    int rowbase = b * 64;
    for (int r = 0; r < 64; ++r) {
        const f32x4* er4 = (const f32x4*)(emb + (rowbase + r) * DD + e * 64);
        float a0 = 0.f, a1 = 0.f, a2 = 0.f, a3 = 0.f;
        DOTp(0, a0)  DOTp(1, a1)  DOTp(2, a2)  DOTp(3, a3)
        DOTp(4, a0)  DOTp(5, a1)  DOTp(6, a2)  DOTp(7, a3)
        DOTp(8, a0)  DOTp(9, a1)  DOTp(10, a2) DOTp(11, a3)
        DOTp(12, a0) DOTp(13, a1) DOTp(14, a2) DOTp(15, a3)
        float half = (a0 + a1) + (a2 + a3);
        float acc = half + __shfl_xor(half, 1);     // both halves get full dot
        float selb  = (float)((sw >> r) & 1ull);
        float goodb = (float)((gw >> r) & 1ull);
        float lm = (selb > 0.f) ? acc : NEGF;
        float nm = fmaxf(m, lm);
        float a = __expf(m - nm);
        float bx = selb * __expf(lm - nm);
        se = se * a + bx;
        sl = sl * a + bx * acc;
        m = nm;
        slg += goodb * acc;
    }
    if (e == 0) {
        int o = b * SS + s;
        part[0 * PARTN + o] = m;
        part[1 * PARTN + o] = se;
        part[2 * PARTN + o] = sl;
        part[3 * PARTN + o] = slg;
        part[4 * PARTN + o] = (float)__popcll(sw);
        part[5 * PARTN + o] = (float)__popcll(gw);
    }
}

// ---------------- per-step merge of 625 block partials -------------------------
__global__ __launch_bounds__(64) void k_reduce(const float* __restrict__ part,
                                               float* __restrict__ Aout,
                                               float* __restrict__ Bout,
                                               float* __restrict__ actout) {
    int s = blockIdx.x;
    int t = threadIdx.x;     // 64 threads, one wave
    float m = NEGF, se = 0.f, sl = 0.f, slg = 0.f, np = 0.f, ng = 0.f;
    for (int b = t; b < NW; b += 64) {
        int o = b * SS + s;
        float m2  = part[0 * PARTN + o];
        float se2 = part[1 * PARTN + o];
        float sl2 = part[2 * PARTN + o];
        slg += part[3 * PARTN + o];
        np  += part[4 * PARTN + o];
        ng  += part[5 * PARTN + o];
        float nm = fmaxf(m, m2);
        float a = __expf(m - nm), a2 = __expf(m2 - nm);
        se = se * a + se2 * a2;
        sl = sl * a + sl2 * a2;
        m = nm;
    }
    for (int off = 32; off > 0; off >>= 1) {
        float m2  = __shfl_xor(m, off);
        float se2 = __shfl_xor(se, off);
        float sl2 = __shfl_xor(sl, off);
        slg += __shfl_xor(slg, off);
        np  += __shfl_xor(np, off);
        ng  += __shfl_xor(ng, off);
        float nm = fmaxf(m, m2);
        float a = __expf(m - nm), a2 = __expf(m2 - nm);
        se = se * a + se2 * a2;
        sl = sl * a + sl2 * a2;
        m = nm;
    }
    if (t == 0) {
        float lse = m + logf(se);
        float nbad = np - ng;
        int active = (ng > 0.5f) && (nbad > 0.5f);
        float ce = (ng * lse - slg) / fmaxf(ng, 1.f);
        float A = (nbad / fmaxf(np, 1.f)) * ce;
        float minus_ent = sl / se - lse;
        float B = ECOEF * (minus_ent / logf(fmaxf(np, 2.0f)));
        Aout[s] = A; Bout[s] = B; actout[s] = active ? 1.f : 0.f;
    }
}

// ---------------- exact sequential discount prefix + final sum -----------------
__global__ __launch_bounds__(64) void k_final(const float* __restrict__ A,
                                              const float* __restrict__ B,
                                              const float* __restrict__ act,
                                              float* __restrict__ out) {
    int lane = threadIdx.x;
    float loss = 0.f;
    int base = 0;
    for (int ch = 0; ch < 8; ++ch) {
        int s = ch * 64 + lane;
        bool a = act[s] > 0.5f;
        unsigned long long bal = __ballot(a);
        unsigned long long ltmask = (lane == 0) ? 0ull : (~0ull >> (64 - lane));
        int pre = __popcll(bal & ltmask);
        if (a) {
            float f = powf(DISCOUNT, (float)(base + pre));
            loss += f * A[s] + B[s];
        }
        base += __popcll(bal);
    }
    for (int off = 32; off > 0; off >>= 1) loss += __shfl_xor(loss, off);
    if (lane == 0) out[0] = loss / fmaxf((float)base, 1.f);
}

extern "C" void kernel_launch(void* const* d_in, const int* in_sizes, int n_in,
                              void* d_out, int out_size, void* d_ws, size_t ws_size,
                              hipStream_t stream) {
    (void)in_sizes; (void)n_in; (void)out_size; (void)ws_size;
    const float* feat    = (const float*)d_in[0];
    const int*   sel     = (const int*)d_in[1];
    const int*   good    = (const int*)d_in[2];
    const int*   sel_idx = (const int*)d_in[3];
    const float* W1      = (const float*)d_in[4];
    const float* b1      = (const float*)d_in[5];
    const float* W2      = (const float*)d_in[6];
    const float* b2      = (const float*)d_in[7];
    const float* init_h  = (const float*)d_in[8];
    const float* init_c  = (const float*)d_in[9];
    const float* Wih     = (const float*)d_in[10];
    const float* Whh     = (const float*)d_in[11];
    const float* bih     = (const float*)d_in[12];
    const float* bhh     = (const float*)d_in[13];
    float* out = (float*)d_out;
    char* ws = (char*)d_ws;

    float* emb    = (float*)(ws + 0);                         // 20,480,000 B
    float* hidden = (float*)(ws + 20480000);                  // 20,480,000 B
    float* P2     = (float*)(ws + 41025536);                  // 1,048,576 B
    float* H      = (float*)(ws + 42074112);                  // 262,144 B
    unsigned long long* selw  = (unsigned long long*)(ws + 42336256);   // 2,560,000 B
    unsigned long long* goodw = (unsigned long long*)(ws + 44896256);   // 2,560,000 B
    float* part   = (float*)(ws + 47456256);                  // 7,680,000 B
    float* Aarr   = (float*)(ws + 55136256);                  // 2048 B
    float* Barr   = (float*)(ws + 55138304);                  // 2048 B
    float* actarr = (float*)(ws + 55140352);                  // 2048 B

    k_pack  <<<1250, 256, 0, stream>>>(sel, good, selw, goodw);
    k_hidden<<<N_CL / 2, 256, 0, stream>>>(feat, W1, b1, hidden);
    k_emb   <<<NW, 256, 0, stream>>>(hidden, W2, b2, emb);
    k_pgemm <<<64, 256, 0, stream>>>(emb, sel_idx, Wih, bih, bhh, P2);
    k_lstm  <<<1, 1024, 0, stream>>>(Whh, P2, init_h, init_c, H);
    k_logits<<<NW * 2, 512, 0, stream>>>(emb, H, selw, goodw, part);
    k_reduce<<<SS, 64, 0, stream>>>(part, Aarr, Barr, actarr);
    k_final <<<1, 64, 0, stream>>>(Aarr, Barr, actarr, out);
}

// Round 8
// 969.090 us; speedup vs baseline: 1.6024x; 1.5302x over previous
//
#include <hip/hip_runtime.h>
#include <stdint.h>

#define N_CL 40000
#define NF   20
#define DD   128
#define SS   512
#define NW   625                 // N_CL / 64
#define PARTN (NW * SS)
#define NEGF (-3.0e38f)
#define DISCOUNT 0.995f
#define ECOEF 0.1f

typedef __attribute__((ext_vector_type(4))) float f32x4;
typedef __attribute__((ext_vector_type(16))) float f32x16;
typedef __attribute__((ext_vector_type(8))) short short8;
typedef __attribute__((ext_vector_type(4))) unsigned short us4;

__device__ __forceinline__ float rl(float v, int k) {
    return __int_as_float(__builtin_amdgcn_readlane(__float_as_int(v), k));
}
__device__ __forceinline__ float rcpf(float x) { return __builtin_amdgcn_rcpf(x); }
__device__ __forceinline__ float sigm(float x) { return rcpf(1.f + __expf(-x)); }
__device__ __forceinline__ float tanh_fast(float x) { return 1.f - 2.f * rcpf(1.f + __expf(2.f * x)); }
__device__ __forceinline__ unsigned short f2bf(float f) {
    unsigned u = __float_as_uint(f);
    return (unsigned short)((u + 0x7fffu + ((u >> 16) & 1u)) >> 16);   // RNE
}
__device__ __forceinline__ float bf2f(unsigned short s) {
    return __uint_as_float(((unsigned)s) << 16);
}

// ------- pack masks: ballot -> u64 words, TRANSPOSED layout [b][s] -------------
__global__ __launch_bounds__(256) void k_pack(const int* __restrict__ sel,
                                              const int* __restrict__ good,
                                              unsigned long long* __restrict__ selw,
                                              unsigned long long* __restrict__ goodw) {
    int wave = (blockIdx.x * 256 + threadIdx.x) >> 6;   // 0..4999
    int lane = threadIdx.x & 63;
    for (int i = 0; i < 64; ++i) {
        int chunk = wave * 64 + i;                      // 0..319999
        int s = chunk / NW;
        int b = chunk - s * NW;
        int idx = s * N_CL + b * 64 + lane;
        unsigned long long bs = __ballot(sel[idx]  != 0);
        unsigned long long bg = __ballot(good[idx] != 0);
        if (lane == 0) { selw[b * SS + s] = bs; goodw[b * SS + s] = bg; }
    }
}

// ---------------- hidden = relu(features @ W1 + b1) ----------------------------
__global__ __launch_bounds__(256) void k_hidden(const float* __restrict__ feat,
                                                const float* __restrict__ W1,
                                                const float* __restrict__ b1,
                                                float* __restrict__ hidden) {
    int t = threadIdx.x;
    int j = t & 127;
    int r = blockIdx.x * 2 + (t >> 7);
    const float* fr = feat + r * NF;
    float acc = b1[j];
#pragma unroll
    for (int f = 0; f < NF; ++f) acc += fr[f] * W1[f * DD + j];
    hidden[r * DD + j] = fmaxf(acc, 0.f);
}

// ------- emb = hidden @ W2 + b2, emitted as bf16 hi/lo pairs -------------------
#define EMB_FMA(RR) { f32x4 hvv = *(const f32x4*)&hs[rg * 8 + RR][q]; \
    acc##RR += wv0 * hvv.x + wv1 * hvv.y + wv2 * hvv.z + wv3 * hvv.w; }
#define EMB_ST(RR) { f32x4 f = acc##RR + bv; us4 hi, lo; \
    hi[0] = f2bf(f.x); lo[0] = f2bf(f.x - bf2f(hi[0])); \
    hi[1] = f2bf(f.y); lo[1] = f2bf(f.y - bf2f(hi[1])); \
    hi[2] = f2bf(f.z); lo[2] = f2bf(f.z - bf2f(hi[2])); \
    hi[3] = f2bf(f.w); lo[3] = f2bf(f.w - bf2f(hi[3])); \
    int row_ = rbase + rg * 8 + RR; \
    *(us4*)&emb_hi[row_ * DD + c4 * 4] = hi; \
    *(us4*)&emb_lo[row_ * DD + c4 * 4] = lo; }

__global__ __launch_bounds__(256) void k_emb(const float* __restrict__ hidden,
                                             const float* __restrict__ W2,
                                             const float* __restrict__ b2,
                                             unsigned short* __restrict__ emb_hi,
                                             unsigned short* __restrict__ emb_lo) {
    __shared__ float hs[64][132];                     // +4 pad, 33.8 KB
    int t = threadIdx.x;
    int rbase = blockIdx.x * 64;
#pragma unroll
    for (int i = t; i < 2048; i += 256) {             // stage 64x128 hidden tile
        int r = i >> 5, k4 = i & 31;
        *(f32x4*)&hs[r][k4 * 4] = *(const f32x4*)&hidden[(rbase + r) * DD + k4 * 4];
    }
    __syncthreads();
    int c4 = t & 31, rg = t >> 5;
    f32x4 acc0{0,0,0,0}, acc1{0,0,0,0}, acc2{0,0,0,0}, acc3{0,0,0,0},
          acc4{0,0,0,0}, acc5{0,0,0,0}, acc6{0,0,0,0}, acc7{0,0,0,0};
    for (int q = 0; q < DD; q += 4) {
        f32x4 wv0 = *(const f32x4*)&W2[(q + 0) * DD + c4 * 4];
        f32x4 wv1 = *(const f32x4*)&W2[(q + 1) * DD + c4 * 4];
        f32x4 wv2 = *(const f32x4*)&W2[(q + 2) * DD + c4 * 4];
        f32x4 wv3 = *(const f32x4*)&W2[(q + 3) * DD + c4 * 4];
        EMB_FMA(0) EMB_FMA(1) EMB_FMA(2) EMB_FMA(3)
        EMB_FMA(4) EMB_FMA(5) EMB_FMA(6) EMB_FMA(7)
    }
    f32x4 bv = *(const f32x4*)&b2[c4 * 4];
    EMB_ST(0) EMB_ST(1) EMB_ST(2) EMB_ST(3)
    EMB_ST(4) EMB_ST(5) EMB_ST(6) EMB_ST(7)
}

// ---- P2[s][pos][g] = bih[j]+bhh[j] + Wih[j].emb[sel_idx[s]],  j=g*128+pos ----
__global__ __launch_bounds__(256) void k_pgemm(const unsigned short* __restrict__ emb_hi,
                                               const unsigned short* __restrict__ emb_lo,
                                               const int* __restrict__ sel_idx,
                                               const float* __restrict__ Wih,
                                               const float* __restrict__ bih,
                                               const float* __restrict__ bhh,
                                               float* __restrict__ P2) {
    __shared__ __align__(16) float x8[8][DD];
    int t = threadIdx.x;
    int sb = blockIdx.x * 8;
    for (int i = t; i < 8 * DD; i += 256) {
        int sl = i >> 7, k = i & 127;
        int idx = sel_idx[sb + sl] * DD + k;
        x8[sl][k] = bf2f(emb_hi[idx]) + bf2f(emb_lo[idx]);
    }
    __syncthreads();
    for (int jj = t; jj < 512; jj += 256) {
        float base = bih[jj] + bhh[jj];
        float acc[8];
#pragma unroll
        for (int s8 = 0; s8 < 8; ++s8) acc[s8] = base;
        const float4* wr = (const float4*)(Wih + jj * DD);
        for (int q = 0; q < 32; ++q) {
            float4 w4 = wr[q];
#pragma unroll
            for (int s8 = 0; s8 < 8; ++s8) {
                const float4* xs = (const float4*)&x8[s8][0];
                float4 xv = xs[q];
                acc[s8] += w4.x * xv.x + w4.y * xv.y + w4.z * xv.z + w4.w * xv.w;
            }
        }
        int pos = jj & 127, g = jj >> 7;
        for (int s8 = 0; s8 < 8; ++s8) P2[(sb + s8) * 512 + pos * 4 + g] = acc[s8];
    }
}

// ------- sequential LSTM scan: 1024 thr, 2 rows x 32 ks / thread ---------------
// H emitted as bf16 hi/lo pairs (H_hi/H_lo [s][128]) for the MFMA phase C.
#define MVQ(WA, WB, KB) { \
    float s0 = rl(vh, (KB) + 0), s1 = rl(vh, (KB) + 1), \
          s2 = rl(vh, (KB) + 2), s3 = rl(vh, (KB) + 3); \
    aA0 = fmaf(WA.x, s0, aA0); aB0 = fmaf(WB.x, s0, aB0); \
    aA1 = fmaf(WA.y, s1, aA1); aB1 = fmaf(WB.y, s1, aB1); \
    aA0 = fmaf(WA.z, s2, aA0); aB0 = fmaf(WB.z, s2, aB0); \
    aA1 = fmaf(WA.w, s3, aA1); aB1 = fmaf(WB.w, s3, aB1); }

__global__ __launch_bounds__(1024, 1) void k_lstm(const float* __restrict__ Whh,
                                                  const float* __restrict__ P2,
                                                  const float* __restrict__ init_h,
                                                  const float* __restrict__ init_c,
                                                  unsigned short* __restrict__ Hhi,
                                                  unsigned short* __restrict__ Hlo) {
    __shared__ __align__(16) float pbuf[2][4096];   // 32 KB: two 8-step P chunks
    __shared__ float psum[4][512];                  // [kq][gate j]
    __shared__ float h_sh[DD];
    int t = threadIdx.x, w = t >> 6, l = t & 63;
    int kq = w & 3, rg = w >> 2;
    int rA = rg * 128 + l, rB = rA + 64;

    const f32x4* wra = (const f32x4*)(Whh + rA * DD + kq * 32);
    const f32x4* wrb = (const f32x4*)(Whh + rB * DD + kq * 32);
    f32x4 wa0 = wra[0], wa1 = wra[1], wa2 = wra[2], wa3 = wra[3],
          wa4 = wra[4], wa5 = wra[5], wa6 = wra[6], wa7 = wra[7];
    f32x4 wb0 = wrb[0], wb1 = wrb[1], wb2 = wrb[2], wb3 = wrb[3],
          wb4 = wrb[4], wb5 = wrb[5], wb6 = wrb[6], wb7 = wrb[7];

    auto issue = [&](int cidx, int bufi) {          // stage one 8-step P chunk
        if (cidx >= SS / 8) return;
        const float* src = P2 + cidx * 4096 + w * 256 + l * 4;
        float* dst = &pbuf[bufi][w * 256];
        __builtin_amdgcn_global_load_lds(
            (const __attribute__((address_space(1))) void*)src,
            (__attribute__((address_space(3))) void*)dst, 16, 0, 0);
    };

    float c = 0.f;
    if (t < DD) {
        float f = init_h[t];
        h_sh[t] = f; c = init_c[t];
        unsigned short hi = f2bf(f);
        Hhi[t] = hi; Hlo[t] = f2bf(f - bf2f(hi));
    }
    issue(0, 0);
    __syncthreads();

    float hbuf[8];
    int hl = kq * 32 + (l & 31);
    for (int s = 0; s < SS; ++s) {
        int buf = (s >> 3) & 1;
        if ((s & 7) == 0) issue((s >> 3) + 1, buf ^ 1);
        float vh = h_sh[hl];                        // lane j holds h[kq*32+j]
        float aA0 = 0.f, aA1 = 0.f, aB0 = 0.f, aB1 = 0.f;
        MVQ(wa0, wb0, 0)  MVQ(wa1, wb1, 4)  MVQ(wa2, wb2, 8)  MVQ(wa3, wb3, 12)
        MVQ(wa4, wb4, 16) MVQ(wa5, wb5, 20) MVQ(wa6, wb6, 24) MVQ(wa7, wb7, 28)
        psum[kq][rA] = aA0 + aA1;                   // stride-1 across lanes
        psum[kq][rB] = aB0 + aB1;
        __syncthreads();
        if (t < DD) {
            float4 pv = *(const float4*)&pbuf[buf][(s & 7) * 512 + t * 4];
            float gi = ((psum[0][t] + psum[1][t]) + (psum[2][t] + psum[3][t])) + pv.x;
            float gf = ((psum[0][128 + t] + psum[1][128 + t]) + (psum[2][128 + t] + psum[3][128 + t])) + pv.y;
            float gg = ((psum[0][256 + t] + psum[1][256 + t]) + (psum[2][256 + t] + psum[3][256 + t])) + pv.z;
            float go = ((psum[0][384 + t] + psum[1][384 + t]) + (psum[2][384 + t] + psum[3][384 + t])) + pv.w;
            float ii = sigm(gi), ff = sigm(gf), tg = tanh_fast(gg), oo = sigm(go);
            c = ff * c + ii * tg;
            float hn = oo * tanh_fast(c);
            h_sh[t] = hn;
            if (s < SS - 1) {
                hbuf[s & 7] = hn;
                if ((s & 7) == 7) {                 // batched H store
#pragma unroll
                    for (int k2 = 0; k2 < 8; ++k2) {
                        float f = hbuf[k2];
                        unsigned short hi = f2bf(f);
                        Hhi[(s - 6 + k2) * DD + t] = hi;
                        Hlo[(s - 6 + k2) * DD + t] = f2bf(f - bf2f(hi));
                    }
                }
            }
        }
        __syncthreads();
    }
    if (t < DD) {                                   // steps 504..510 -> H[505..511]
#pragma unroll
        for (int k2 = 0; k2 < 7; ++k2) {
            float f = hbuf[k2];
            unsigned short hi = f2bf(f);
            Hhi[(505 + k2) * DD + t] = hi;
            Hlo[(505 + k2) * DD + t] = f2bf(f - bf2f(hi));
        }
    }
}

// ------- phase C: MFMA GEMM logits + masked-softmax epilogue -------------------
// Grid 2500: b = blk>>2 (64-row tile), (blk&3, wave) -> 32-step group.
// Per wave: D[64 rows x 32 steps] via 32x32x16 bf16 MFMA, 3 hi/lo passes fused
// into the accumulator. C-layout: col(=step)=lane&31, row=(reg&3)+8*(reg>>2)
// +4*(lane>>5) (+32 for tile1). Lanes l and l^32 hold the 64 rows of step l&31.
__global__ __launch_bounds__(256, 1) void k_logits(
        const unsigned short* __restrict__ emb_hi,
        const unsigned short* __restrict__ emb_lo,
        const unsigned short* __restrict__ Hhi,
        const unsigned short* __restrict__ Hlo,
        const unsigned long long* __restrict__ selw,
        const unsigned long long* __restrict__ goodw,
        float* __restrict__ part) {
    int blk = blockIdx.x;
    int b = blk >> 2;
    int t = threadIdx.x, wv = t >> 6, l = t & 63;
    int s0 = (blk & 3) * 128 + wv * 32;
    int ln = l & 31, lh = l >> 5;
    int rb = b * 64;
    const short8* A0h = (const short8*)(emb_hi + (rb + ln) * DD + lh * 8);
    const short8* A0l = (const short8*)(emb_lo + (rb + ln) * DD + lh * 8);
    const short8* A1h = (const short8*)(emb_hi + (rb + 32 + ln) * DD + lh * 8);
    const short8* A1l = (const short8*)(emb_lo + (rb + 32 + ln) * DD + lh * 8);
    const short8* Bhp = (const short8*)(Hhi + (s0 + ln) * DD + lh * 8);
    const short8* Blp = (const short8*)(Hlo + (s0 + ln) * DD + lh * 8);
    f32x16 acc0, acc1;
#pragma unroll
    for (int r = 0; r < 16; ++r) { acc0[r] = 0.f; acc1[r] = 0.f; }
#pragma unroll
    for (int kc = 0; kc < 8; ++kc) {               // K = 8 x 16
        short8 a0h = A0h[kc * 2], a0l = A0l[kc * 2];
        short8 a1h = A1h[kc * 2], a1l = A1l[kc * 2];
        short8 bh = Bhp[kc * 2], bl = Blp[kc * 2];
        acc0 = __builtin_amdgcn_mfma_f32_32x32x16_bf16(a0h, bh, acc0, 0, 0, 0);
        acc0 = __builtin_amdgcn_mfma_f32_32x32x16_bf16(a0l, bh, acc0, 0, 0, 0);
        acc0 = __builtin_amdgcn_mfma_f32_32x32x16_bf16(a0h, bl, acc0, 0, 0, 0);
        acc1 = __builtin_amdgcn_mfma_f32_32x32x16_bf16(a1h, bh, acc1, 0, 0, 0);
        acc1 = __builtin_amdgcn_mfma_f32_32x32x16_bf16(a1l, bh, acc1, 0, 0, 0);
        acc1 = __builtin_amdgcn_mfma_f32_32x32x16_bf16(a1h, bl, acc1, 0, 0, 0);
    }
    int s = s0 + ln;
    unsigned long long sw = selw[b * SS + s];      // coalesced, [b][s] layout
    unsigned long long gw = goodw[b * SS + s];
    float m = NEGF;
#pragma unroll
    for (int r = 0; r < 16; ++r) {
        int row = (r & 3) + 8 * (r >> 2) + 4 * lh;
        float v0 = acc0[r], v1 = acc1[r];
        m = fmaxf(m, ((sw >> row) & 1ull) ? v0 : NEGF);
        m = fmaxf(m, ((sw >> (row + 32)) & 1ull) ? v1 : NEGF);
    }
    m = fmaxf(m, __shfl_xor(m, 32));
    float se = 0.f, sl = 0.f, slg = 0.f;
#pragma unroll
    for (int r = 0; r < 16; ++r) {
        int row = (r & 3) + 8 * (r >> 2) + 4 * lh;
        float v0 = acc0[r], v1 = acc1[r];
        float e0 = ((sw >> row) & 1ull) ? __expf(v0 - m) : 0.f;
        float e1 = ((sw >> (row + 32)) & 1ull) ? __expf(v1 - m) : 0.f;
        se += e0 + e1;
        sl += e0 * v0 + e1 * v1;
        slg += (((gw >> row) & 1ull) ? v0 : 0.f)
             + (((gw >> (row + 32)) & 1ull) ? v1 : 0.f);
    }
    se += __shfl_xor(se, 32);
    sl += __shfl_xor(sl, 32);
    slg += __shfl_xor(slg, 32);
    if (lh == 0) {
        int o = b * SS + s;
        part[0 * PARTN + o] = m;
        part[1 * PARTN + o] = se;
        part[2 * PARTN + o] = sl;
        part[3 * PARTN + o] = slg;
        part[4 * PARTN + o] = (float)__popcll(sw);
        part[5 * PARTN + o] = (float)__popcll(gw);
    }
}

// ---------------- per-step merge of 625 block partials -------------------------
__global__ __launch_bounds__(64) void k_reduce(const float* __restrict__ part,
                                               float* __restrict__ Aout,
                                               float* __restrict__ Bout,
                                               float* __restrict__ actout) {
    int s = blockIdx.x;
    int t = threadIdx.x;     // 64 threads, one wave
    float m = NEGF, se = 0.f, sl = 0.f, slg = 0.f, np = 0.f, ng = 0.f;
    for (int b = t; b < NW; b += 64) {
        int o = b * SS + s;
        float m2  = part[0 * PARTN + o];
        float se2 = part[1 * PARTN + o];
        float sl2 = part[2 * PARTN + o];
        slg += part[3 * PARTN + o];
        np  += part[4 * PARTN + o];
        ng  += part[5 * PARTN + o];
        float nm = fmaxf(m, m2);
        float a = __expf(m - nm), a2 = __expf(m2 - nm);
        se = se * a + se2 * a2;
        sl = sl * a + sl2 * a2;
        m = nm;
    }
    for (int off = 32; off > 0; off >>= 1) {
        float m2  = __shfl_xor(m, off);
        float se2 = __shfl_xor(se, off);
        float sl2 = __shfl_xor(sl, off);
        slg += __shfl_xor(slg, off);
        np  += __shfl_xor(np, off);
        ng  += __shfl_xor(ng, off);
        float nm = fmaxf(m, m2);
        float a = __expf(m - nm), a2 = __expf(m2 - nm);
        se = se * a + se2 * a2;
        sl = sl * a + sl2 * a2;
        m = nm;
    }
    if (t == 0) {
        float lse = m + logf(se);
        float nbad = np - ng;
        int active = (ng > 0.5f) && (nbad > 0.5f);
        float ce = (ng * lse - slg) / fmaxf(ng, 1.f);
        float A = (nbad / fmaxf(np, 1.f)) * ce;
        float minus_ent = sl / se - lse;
        float B = ECOEF * (minus_ent / logf(fmaxf(np, 2.0f)));
        Aout[s] = A; Bout[s] = B; actout[s] = active ? 1.f : 0.f;
    }
}

// ---------------- exact sequential discount prefix + final sum -----------------
__global__ __launch_bounds__(64) void k_final(const float* __restrict__ A,
                                              const float* __restrict__ B,
                                              const float* __restrict__ act,
                                              float* __restrict__ out) {
    int lane = threadIdx.x;
    float loss = 0.f;
    int base = 0;
    for (int ch = 0; ch < 8; ++ch) {
        int s = ch * 64 + lane;
        bool a = act[s] > 0.5f;
        unsigned long long bal = __ballot(a);
        unsigned long long ltmask = (lane == 0) ? 0ull : (~0ull >> (64 - lane));
        int pre = __popcll(bal & ltmask);
        if (a) {
            float f = powf(DISCOUNT, (float)(base + pre));
            loss += f * A[s] + B[s];
        }
        base += __popcll(bal);
    }
    for (int off = 32; off > 0; off >>= 1) loss += __shfl_xor(loss, off);
    if (lane == 0) out[0] = loss / fmaxf((float)base, 1.f);
}

extern "C" void kernel_launch(void* const* d_in, const int* in_sizes, int n_in,
                              void* d_out, int out_size, void* d_ws, size_t ws_size,
                              hipStream_t stream) {
    (void)in_sizes; (void)n_in; (void)out_size; (void)ws_size;
    const float* feat    = (const float*)d_in[0];
    const int*   sel     = (const int*)d_in[1];
    const int*   good    = (const int*)d_in[2];
    const int*   sel_idx = (const int*)d_in[3];
    const float* W1      = (const float*)d_in[4];
    const float* b1      = (const float*)d_in[5];
    const float* W2      = (const float*)d_in[6];
    const float* b2      = (const float*)d_in[7];
    const float* init_h  = (const float*)d_in[8];
    const float* init_c  = (const float*)d_in[9];
    const float* Wih     = (const float*)d_in[10];
    const float* Whh     = (const float*)d_in[11];
    const float* bih     = (const float*)d_in[12];
    const float* bhh     = (const float*)d_in[13];
    float* out = (float*)d_out;
    char* ws = (char*)d_ws;

    float*          hidden = (float*)(ws + 0);                    // 20,480,000 B
    unsigned short* emb_hi = (unsigned short*)(ws + 20480000);    // 10,240,000 B
    unsigned short* emb_lo = (unsigned short*)(ws + 30720000);    // 10,240,000 B
    float*          P2     = (float*)(ws + 40960000);             //  1,048,576 B
    unsigned short* Hhi    = (unsigned short*)(ws + 42008576);    //    131,072 B
    unsigned short* Hlo    = (unsigned short*)(ws + 42139648);    //    131,072 B
    unsigned long long* selw  = (unsigned long long*)(ws + 42270720);  // 2,560,000 B
    unsigned long long* goodw = (unsigned long long*)(ws + 44830720);  // 2,560,000 B
    float*          part   = (float*)(ws + 47390720);             //  7,680,000 B
    float*          Aarr   = (float*)(ws + 55070720);             //      2,048 B
    float*          Barr   = (float*)(ws + 55072768);             //      2,048 B
    float*          actarr = (float*)(ws + 55074816);             //      2,048 B

    k_pack  <<<1250, 256, 0, stream>>>(sel, good, selw, goodw);
    k_hidden<<<N_CL / 2, 256, 0, stream>>>(feat, W1, b1, hidden);
    k_emb   <<<NW, 256, 0, stream>>>(hidden, W2, b2, emb_hi, emb_lo);
    k_pgemm <<<64, 256, 0, stream>>>(emb_hi, emb_lo, sel_idx, Wih, bih, bhh, P2);
    k_lstm  <<<1, 1024, 0, stream>>>(Whh, P2, init_h, init_c, Hhi, Hlo);
    k_logits<<<NW * 4, 256, 0, stream>>>(emb_hi, emb_lo, Hhi, Hlo, selw, goodw, part);
    k_reduce<<<SS, 64, 0, stream>>>(part, Aarr, Barr, actarr);
    k_final <<<1, 64, 0, stream>>>(Aarr, Barr, actarr, out);
}